// Round 16
// baseline (47.987 us; speedup 1.0000x reference)
//
#include <hip/hip_runtime.h>
#include <hip/hip_bf16.h>
#include <hip/hip_fp8.h>

// SimCLR NT-Xent loss v16: R15 fp8 core pushed to 4 blocks/CU —
// __launch_bounds__(256,4), 32 even column splits (NT=4, no tail imbalance),
// grid 1024. Register fit: afA/afB 64 + acc 16 + m/s 16 + temps ~= 120 < 128.
// Everything else identical to R15 (best: 34.75 us).

#define NROWS 4096
#define DDIM  512
#define NSPLIT 32                // even splits: 4 tiles of 32 cols each
#define BM 128                   // rows per block (4 waves x 32)
#define NEG_BIG (-3.0e38f)
#define SQRT_CSCALE 3.798282562f // sqrt(10*log2(e)); (sqrt(c)A)(sqrt(c)B) = c*sim
#define LN2 0.69314718055994530942f
#define THR 40.0f                // defer-max threshold (log2 units)

typedef float f32x4 __attribute__((ext_vector_type(4)));
typedef long  lx2   __attribute__((ext_vector_type(2)));

#define GLOAD_LDS16(g, l) __builtin_amdgcn_global_load_lds(                    \
    (const __attribute__((address_space(1))) void*)(g),                        \
    (__attribute__((address_space(3))) void*)(l), 16, 0, 0)

#define MFMA8(a, b, c) __builtin_amdgcn_mfma_f32_16x16x32_fp8_fp8((a), (b), (c), 0, 0, 0)

// ---------------- kernel 0: fp32 -> fp8 e4m3, scaled, fragment-ordered ----------------
// out byte for (row, k): row*512 + lk*128 + kb*8 + e, where k = kb*32 + lk*8 + e.
// thread t (0..63 per row) handles k in [8t, 8t+8) = (kb = t>>2, lk = t&3).
__global__ void jl_cvt(const float* __restrict__ in, unsigned char* __restrict__ out) {
    const int i   = blockIdx.x * 256 + threadIdx.x;
    const int row = i >> 6;
    const int t   = i & 63;
    const float* src = in + (size_t)row * DDIM + t * 8;
    float4 x = *(const float4*)(src);
    float4 y = *(const float4*)(src + 4);
    float v[8] = {x.x, x.y, x.z, x.w, y.x, y.y, y.z, y.w};
    unsigned long long pk = 0;
    #pragma unroll
    for (int e = 0; e < 8; ++e) {
        __hip_fp8_e4m3 f(v[e] * SQRT_CSCALE);
        pk |= (unsigned long long)f.__x << (8 * e);
    }
    *(unsigned long long*)(out + (size_t)row * 512 + (t & 3) * 128 + (t >> 2) * 8) = pk;
}

// ---------------- kernel 1: fused fp8 GEMM + log2-sum-exp2 partials ----------------
// grid = 32 rowblocks x 32 colsplits = 1024 blocks (4/CU), 256 threads (4 waves).
// split q: tiles [4q, 4q+4) of 32 cols x K512 each.
__global__ __launch_bounds__(256, 4) void jl_main(const unsigned char* __restrict__ rb,
                                                  float* __restrict__ pm,
                                                  float* __restrict__ ps,
                                                  float* __restrict__ pos) {
    // 2 buffers x 32 tile-cols x 512 B (fragment-ordered, XOR-swizzled 16B slots)
    __shared__ __align__(16) char smem[2][32][512];

    const int rbk   = blockIdx.x >> 5;   // 0..31
    const int q     = blockIdx.x & 31;   // 0..31
    const int tile0 = q * 4;
    const int NTq   = 4;

    const int wave = threadIdx.x >> 6;
    const int lane = threadIdx.x & 63;
    const int row0 = rbk * BM + wave * 32;   // wave's first row (32 rows)
    const int lrow = lane & 15;
    const int lk   = lane >> 4;
    const int swz  = (lrow & 7) << 4;        // read-side XOR (byte units)
    const char* rbb = (const char*)rb;       // fp8 row stride 512 B

    // A fragments: 32 longs = 64 VGPR. afA[kb] = A[row0+lrow][k=kb*32+lk*8+..]
    long afA[16], afB[16];
    {
        const char* ar = rbb + (size_t)(row0 + lrow) * 512 + lk * 128;
        #pragma unroll
        for (int j = 0; j < 8; ++j) {
            lx2 v = *(const lx2*)(ar + j * 16);
            lx2 w = *(const lx2*)(ar + 16 * 512 + j * 16);
            afA[2 * j] = v[0]; afA[2 * j + 1] = v[1];
            afB[2 * j] = w[0]; afB[2 * j + 1] = w[1];
        }
    }

    // staging: wave w stages tile-cols [8w, 8w+8) as 4 x 1KB gload_lds (2 cols each).
    // per-lane source: col c = base + (lane>>5), slot s = lane&31,
    // global byte = c*512 + (s*16 ^ ((c&7)<<4))  [inverse of the read swizzle]
#define STAGE(J)                                                               \
    do {                                                                       \
        _Pragma("unroll")                                                      \
        for (int i_ = 0; i_ < 4; ++i_) {                                       \
            const int lc_ = wave * 8 + 2 * i_;            /* local col pair */ \
            const int c_  = (tile0 + (J)) * 32 + lc_ + (lane >> 5);            \
            const char* g_ = rbb + (size_t)c_ * 512                            \
                             + (((lane & 31) * 16) ^ ((c_ & 7) << 4));         \
            GLOAD_LDS16(g_, &smem[(J) & 1][lc_][0]);                           \
        }                                                                      \
    } while (0)

    STAGE(0);

    float m[2][4], s[2][4];
    #pragma unroll
    for (int h = 0; h < 2; ++h)
        #pragma unroll
        for (int r = 0; r < 4; ++r) { m[h][r] = NEG_BIG; s[h][r] = 0.0f; }

    for (int jt = 0; jt < NTq; ++jt) {
        // race-free 2-phase: drain own stage loads, sync, then prefetch next
        asm volatile("s_waitcnt vmcnt(0)" ::: "memory");
        __builtin_amdgcn_s_barrier();
        __builtin_amdgcn_sched_barrier(0);
        if (jt + 1 < NTq) STAGE(jt + 1);

        const int cb = jt & 1;

        f32x4 a00 = {0.f,0.f,0.f,0.f}, a01 = {0.f,0.f,0.f,0.f};
        f32x4 a10 = {0.f,0.f,0.f,0.f}, a11 = {0.f,0.f,0.f,0.f};
        __builtin_amdgcn_s_setprio(1);
        #pragma unroll
        for (int j = 0; j < 8; ++j) {
            // b128 at fragment offset (lk*128 + j*16) ^ swz covers kb=2j, 2j+1
            lx2 b0 = *(const lx2*)(&smem[cb][lrow][0]      + ((lk * 128 + j * 16) ^ swz));
            lx2 b1 = *(const lx2*)(&smem[cb][16 + lrow][0] + ((lk * 128 + j * 16) ^ swz));
            a00 = MFMA8(afA[2 * j],     b0[0], a00);
            a10 = MFMA8(afB[2 * j],     b0[0], a10);
            a01 = MFMA8(afA[2 * j],     b1[0], a01);
            a11 = MFMA8(afB[2 * j],     b1[0], a11);
            a00 = MFMA8(afA[2 * j + 1], b0[1], a00);
            a10 = MFMA8(afB[2 * j + 1], b0[1], a10);
            a01 = MFMA8(afA[2 * j + 1], b1[1], a01);
            a11 = MFMA8(afB[2 * j + 1], b1[1], a11);
        }
        __builtin_amdgcn_s_setprio(0);

        // y[h][n]: row = row0 + h*16 + 4*lk + r,  col = ctile + n*16 + lrow
        f32x4 y[2][2] = {{a00, a01}, {a10, a11}};
        const int ctile = (tile0 + jt) * 32;   // wave-uniform absolute column

        // positive-pair tile (uniform, rare): partner of row i is i^2048
        if (ctile == (row0 ^ 2048)) {
            #pragma unroll
            for (int h = 0; h < 2; ++h)
                #pragma unroll
                for (int r = 0; r < 4; ++r)
                    if (lrow == 4 * lk + r)
                        pos[row0 + h * 16 + 4 * lk + r] = y[h][h][r];
        }

        if (ctile == row0) {
            // diagonal tile (1 per wave): mask col==row then full online update
            #pragma unroll
            for (int h = 0; h < 2; ++h)
                #pragma unroll
                for (int r = 0; r < 4; ++r) {
                    if (lrow == 4 * lk + r) y[h][h][r] = NEG_BIG;
                    float y0 = y[h][0][r], y1 = y[h][1][r];
                    float mn = fmaxf(m[h][r], fmaxf(y0, y1));
                    s[h][r] = s[h][r] * __builtin_amdgcn_exp2f(m[h][r] - mn)
                            + __builtin_amdgcn_exp2f(y0 - mn)
                            + __builtin_amdgcn_exp2f(y1 - mn);
                    m[h][r] = mn;
                }
        } else {
            float t[2][2][4];
            float dmax = NEG_BIG;
            #pragma unroll
            for (int h = 0; h < 2; ++h)
                #pragma unroll
                for (int n = 0; n < 2; ++n)
                    #pragma unroll
                    for (int r = 0; r < 4; ++r) {
                        t[h][n][r] = y[h][n][r] - m[h][r];
                        dmax = fmaxf(dmax, t[h][n][r]);
                    }
            if (__any(dmax > THR)) {
                #pragma unroll
                for (int h = 0; h < 2; ++h)
                    #pragma unroll
                    for (int r = 0; r < 4; ++r) {
                        float y0 = y[h][0][r], y1 = y[h][1][r];
                        float mn = fmaxf(m[h][r], fmaxf(y0, y1));
                        s[h][r] = s[h][r] * __builtin_amdgcn_exp2f(m[h][r] - mn)
                                + __builtin_amdgcn_exp2f(y0 - mn)
                                + __builtin_amdgcn_exp2f(y1 - mn);
                        m[h][r] = mn;
                    }
            } else {
                #pragma unroll
                for (int h = 0; h < 2; ++h)
                    #pragma unroll
                    for (int r = 0; r < 4; ++r)
                        s[h][r] += __builtin_amdgcn_exp2f(t[h][0][r])
                                 + __builtin_amdgcn_exp2f(t[h][1][r]);
            }
        }
    }
#undef STAGE

    // merge (m,s) across the 16 lanes of each row group, write partials
    #pragma unroll
    for (int h = 0; h < 2; ++h)
        #pragma unroll
        for (int r = 0; r < 4; ++r) {
            float mm = m[h][r], ss = s[h][r];
            #pragma unroll
            for (int off = 1; off < 16; off <<= 1) {
                float mo = __shfl_xor(mm, off, 64);
                float so = __shfl_xor(ss, off, 64);
                float mn = fmaxf(mm, mo);
                ss = ss * __builtin_amdgcn_exp2f(mm - mn)
                   + so * __builtin_amdgcn_exp2f(mo - mn);
                mm = mn;
            }
            if (lrow == 0) {
                const int grow = row0 + 16 * h + 4 * lk + r;
                pm[grow * NSPLIT + q] = mm;
                ps[grow * NSPLIT + q] = ss;
            }
        }
}

// ---------------- kernel 2a: per-row loss + per-block partial sum ----------------
__global__ void jl_rowloss(const float* __restrict__ pm, const float* __restrict__ ps,
                           const float* __restrict__ pos, float* __restrict__ part) {
    __shared__ float red[256];
    const int t = threadIdx.x;
    const int row = blockIdx.x * 256 + t;
    float mb = NEG_BIG;
    #pragma unroll
    for (int qq = 0; qq < NSPLIT; ++qq) mb = fmaxf(mb, pm[row * NSPLIT + qq]);
    float st = 0.0f;
    #pragma unroll
    for (int qq = 0; qq < NSPLIT; ++qq)
        st += ps[row * NSPLIT + qq] * __builtin_amdgcn_exp2f(pm[row * NSPLIT + qq] - mb);
    red[t] = mb + __builtin_amdgcn_logf(st) - pos[row];
    __syncthreads();
    for (int off = 128; off > 0; off >>= 1) {
        if (t < off) red[t] += red[t + off];
        __syncthreads();
    }
    if (t == 0) part[blockIdx.x] = red[0];
}

// ---------------- kernel 2b: final reduce ----------------
__global__ void jl_final(const float* __restrict__ part, float* __restrict__ out) {
    const int t = threadIdx.x;
    float v = (t < NROWS / 256) ? part[t] : 0.0f;
    #pragma unroll
    for (int off = 1; off < 16; off <<= 1) v += __shfl_xor(v, off, 64);
    if (t == 0) out[0] = v * (LN2 / (float)NROWS);
}

extern "C" void kernel_launch(void* const* d_in, const int* in_sizes, int n_in,
                              void* d_out, int out_size, void* d_ws, size_t ws_size,
                              hipStream_t stream) {
    const float* rep = (const float*)d_in[0];
    float* out = (float*)d_out;

    unsigned char* rbuf = (unsigned char*)d_ws;                  // 2 MB fp8
    float*  pm   = (float*)(rbuf + (size_t)NROWS * 512);
    float*  ps   = pm + NROWS * NSPLIT;
    float*  pos  = ps + NROWS * NSPLIT;
    float*  part = pos + NROWS;

    jl_cvt<<<(NROWS * 64) / 256, 256, 0, stream>>>(rep, rbuf);
    jl_main<<<32 * NSPLIT, 256, 0, stream>>>(rbuf, pm, ps, pos);
    jl_rowloss<<<NROWS / 256, 256, 0, stream>>>(pm, ps, pos, part);
    jl_final<<<1, 64, 0, stream>>>(part, out);
}

// Round 17
// 37.250 us; speedup vs baseline: 1.2882x; 1.2882x over previous
//
#include <hip/hip_runtime.h>
#include <hip/hip_bf16.h>
#include <hip/hip_fp8.h>

// SimCLR NT-Xent loss v17: R15 fp8 core (best: 34.75us) kept byte-identical.
// Edges trimmed: (1) hardware-packed fp8 convert (v_cvt_pk_fp8_f32),
// (2) jl_final dropped — rowloss atomicAdds into memset-zeroed out[0].

#define NROWS 4096
#define DDIM  512
#define NSPLIT 24                // uneven splits: 16 x 5 tiles + 8 x 6 tiles (128 tiles)
#define BM 128                   // rows per block (4 waves x 32)
#define NEG_BIG (-3.0e38f)
#define SQRT_CSCALE 3.798282562f // sqrt(10*log2(e)); (sqrt(c)A)(sqrt(c)B) = c*sim
#define LN2 0.69314718055994530942f
#define THR 40.0f                // defer-max threshold (log2 units)

typedef float f32x4 __attribute__((ext_vector_type(4)));
typedef long  lx2   __attribute__((ext_vector_type(2)));

#define GLOAD_LDS16(g, l) __builtin_amdgcn_global_load_lds(                    \
    (const __attribute__((address_space(1))) void*)(g),                        \
    (__attribute__((address_space(3))) void*)(l), 16, 0, 0)

#define MFMA8(a, b, c) __builtin_amdgcn_mfma_f32_16x16x32_fp8_fp8((a), (b), (c), 0, 0, 0)

// ---------------- kernel 0: fp32 -> fp8 e4m3 (HW packed cvt), fragment-ordered ----------------
// out byte for (row, k): row*512 + lk*128 + kb*8 + e, where k = kb*32 + lk*8 + e.
// thread t (0..63 per row) handles k in [8t, 8t+8) = (kb = t>>2, lk = t&3).
__global__ void jl_cvt(const float* __restrict__ in, unsigned char* __restrict__ out) {
    const int i   = blockIdx.x * 256 + threadIdx.x;
    const int row = i >> 6;
    const int t   = i & 63;
    const float* src = in + (size_t)row * DDIM + t * 8;
    float4 x = *(const float4*)(src);
    float4 y = *(const float4*)(src + 4);
    int w0 = __builtin_amdgcn_cvt_pk_fp8_f32(x.x * SQRT_CSCALE, x.y * SQRT_CSCALE, 0, false);
    w0     = __builtin_amdgcn_cvt_pk_fp8_f32(x.z * SQRT_CSCALE, x.w * SQRT_CSCALE, w0, true);
    int w1 = __builtin_amdgcn_cvt_pk_fp8_f32(y.x * SQRT_CSCALE, y.y * SQRT_CSCALE, 0, false);
    w1     = __builtin_amdgcn_cvt_pk_fp8_f32(y.z * SQRT_CSCALE, y.w * SQRT_CSCALE, w1, true);
    uint2 pk = {(unsigned)w0, (unsigned)w1};
    *(uint2*)(out + (size_t)row * 512 + (t & 3) * 128 + (t >> 2) * 8) = pk;
}

// ---------------- kernel 1: fused fp8 GEMM + log2-sum-exp2 partials (R15 exact) ----------------
// grid = 32 rowblocks x 24 colsplits = 768 blocks (3/CU), 256 threads (4 waves).
// split q: tiles [tile0, tile0+NTq) of 32 cols x K512 each.
__global__ __launch_bounds__(256, 3) void jl_main(const unsigned char* __restrict__ rb,
                                                  float* __restrict__ pm,
                                                  float* __restrict__ ps,
                                                  float* __restrict__ pos) {
    // 2 buffers x 32 tile-cols x 512 B (fragment-ordered, XOR-swizzled 16B slots)
    __shared__ __align__(16) char smem[2][32][512];

    const int rbk   = blockIdx.x / NSPLIT;   // 0..31
    const int q     = blockIdx.x % NSPLIT;   // 0..23
    const int tile0 = (q < 16) ? 5 * q : 80 + 6 * (q - 16);
    const int NTq   = (q < 16) ? 5 : 6;

    const int wave = threadIdx.x >> 6;
    const int lane = threadIdx.x & 63;
    const int row0 = rbk * BM + wave * 32;   // wave's first row (32 rows)
    const int lrow = lane & 15;
    const int lk   = lane >> 4;
    const int swz  = (lrow & 7) << 4;        // read-side XOR (byte units)
    const char* rbb = (const char*)rb;       // fp8 row stride 512 B

    // A fragments: 32 longs = 64 VGPR. afA[kb] = A[row0+lrow][k=kb*32+lk*8+..]
    long afA[16], afB[16];
    {
        const char* ar = rbb + (size_t)(row0 + lrow) * 512 + lk * 128;
        #pragma unroll
        for (int j = 0; j < 8; ++j) {
            lx2 v = *(const lx2*)(ar + j * 16);
            lx2 w = *(const lx2*)(ar + 16 * 512 + j * 16);
            afA[2 * j] = v[0]; afA[2 * j + 1] = v[1];
            afB[2 * j] = w[0]; afB[2 * j + 1] = w[1];
        }
    }

    // staging: wave w stages tile-cols [8w, 8w+8) as 4 x 1KB gload_lds (2 cols each).
    // per-lane source: col c = base + (lane>>5), slot s = lane&31,
    // global byte = c*512 + (s*16 ^ ((c&7)<<4))  [inverse of the read swizzle]
#define STAGE(J)                                                               \
    do {                                                                       \
        _Pragma("unroll")                                                      \
        for (int i_ = 0; i_ < 4; ++i_) {                                       \
            const int lc_ = wave * 8 + 2 * i_;            /* local col pair */ \
            const int c_  = (tile0 + (J)) * 32 + lc_ + (lane >> 5);            \
            const char* g_ = rbb + (size_t)c_ * 512                            \
                             + (((lane & 31) * 16) ^ ((c_ & 7) << 4));         \
            GLOAD_LDS16(g_, &smem[(J) & 1][lc_][0]);                           \
        }                                                                      \
    } while (0)

    STAGE(0);

    float m[2][4], s[2][4];
    #pragma unroll
    for (int h = 0; h < 2; ++h)
        #pragma unroll
        for (int r = 0; r < 4; ++r) { m[h][r] = NEG_BIG; s[h][r] = 0.0f; }

    for (int jt = 0; jt < NTq; ++jt) {
        // race-free 2-phase: drain own stage loads, sync, then prefetch next
        asm volatile("s_waitcnt vmcnt(0)" ::: "memory");
        __builtin_amdgcn_s_barrier();
        __builtin_amdgcn_sched_barrier(0);
        if (jt + 1 < NTq) STAGE(jt + 1);

        const int cb = jt & 1;

        f32x4 a00 = {0.f,0.f,0.f,0.f}, a01 = {0.f,0.f,0.f,0.f};
        f32x4 a10 = {0.f,0.f,0.f,0.f}, a11 = {0.f,0.f,0.f,0.f};
        __builtin_amdgcn_s_setprio(1);
        #pragma unroll
        for (int j = 0; j < 8; ++j) {
            // b128 at fragment offset (lk*128 + j*16) ^ swz covers kb=2j, 2j+1
            lx2 b0 = *(const lx2*)(&smem[cb][lrow][0]      + ((lk * 128 + j * 16) ^ swz));
            lx2 b1 = *(const lx2*)(&smem[cb][16 + lrow][0] + ((lk * 128 + j * 16) ^ swz));
            a00 = MFMA8(afA[2 * j],     b0[0], a00);
            a10 = MFMA8(afB[2 * j],     b0[0], a10);
            a01 = MFMA8(afA[2 * j],     b1[0], a01);
            a11 = MFMA8(afB[2 * j],     b1[0], a11);
            a00 = MFMA8(afA[2 * j + 1], b0[1], a00);
            a10 = MFMA8(afB[2 * j + 1], b0[1], a10);
            a01 = MFMA8(afA[2 * j + 1], b1[1], a01);
            a11 = MFMA8(afB[2 * j + 1], b1[1], a11);
        }
        __builtin_amdgcn_s_setprio(0);

        // y[h][n]: row = row0 + h*16 + 4*lk + r,  col = ctile + n*16 + lrow
        f32x4 y[2][2] = {{a00, a01}, {a10, a11}};
        const int ctile = (tile0 + jt) * 32;   // wave-uniform absolute column

        // positive-pair tile (uniform, rare): partner of row i is i^2048
        if (ctile == (row0 ^ 2048)) {
            #pragma unroll
            for (int h = 0; h < 2; ++h)
                #pragma unroll
                for (int r = 0; r < 4; ++r)
                    if (lrow == 4 * lk + r)
                        pos[row0 + h * 16 + 4 * lk + r] = y[h][h][r];
        }

        if (ctile == row0) {
            // diagonal tile (1 per wave): mask col==row then full online update
            #pragma unroll
            for (int h = 0; h < 2; ++h)
                #pragma unroll
                for (int r = 0; r < 4; ++r) {
                    if (lrow == 4 * lk + r) y[h][h][r] = NEG_BIG;
                    float y0 = y[h][0][r], y1 = y[h][1][r];
                    float mn = fmaxf(m[h][r], fmaxf(y0, y1));
                    s[h][r] = s[h][r] * __builtin_amdgcn_exp2f(m[h][r] - mn)
                            + __builtin_amdgcn_exp2f(y0 - mn)
                            + __builtin_amdgcn_exp2f(y1 - mn);
                    m[h][r] = mn;
                }
        } else {
            float t[2][2][4];
            float dmax = NEG_BIG;
            #pragma unroll
            for (int h = 0; h < 2; ++h)
                #pragma unroll
                for (int n = 0; n < 2; ++n)
                    #pragma unroll
                    for (int r = 0; r < 4; ++r) {
                        t[h][n][r] = y[h][n][r] - m[h][r];
                        dmax = fmaxf(dmax, t[h][n][r]);
                    }
            if (__any(dmax > THR)) {
                #pragma unroll
                for (int h = 0; h < 2; ++h)
                    #pragma unroll
                    for (int r = 0; r < 4; ++r) {
                        float y0 = y[h][0][r], y1 = y[h][1][r];
                        float mn = fmaxf(m[h][r], fmaxf(y0, y1));
                        s[h][r] = s[h][r] * __builtin_amdgcn_exp2f(m[h][r] - mn)
                                + __builtin_amdgcn_exp2f(y0 - mn)
                                + __builtin_amdgcn_exp2f(y1 - mn);
                        m[h][r] = mn;
                    }
            } else {
                #pragma unroll
                for (int h = 0; h < 2; ++h)
                    #pragma unroll
                    for (int r = 0; r < 4; ++r)
                        s[h][r] += __builtin_amdgcn_exp2f(t[h][0][r])
                                 + __builtin_amdgcn_exp2f(t[h][1][r]);
            }
        }
    }
#undef STAGE

    // merge (m,s) across the 16 lanes of each row group, write partials
    #pragma unroll
    for (int h = 0; h < 2; ++h)
        #pragma unroll
        for (int r = 0; r < 4; ++r) {
            float mm = m[h][r], ss = s[h][r];
            #pragma unroll
            for (int off = 1; off < 16; off <<= 1) {
                float mo = __shfl_xor(mm, off, 64);
                float so = __shfl_xor(ss, off, 64);
                float mn = fmaxf(mm, mo);
                ss = ss * __builtin_amdgcn_exp2f(mm - mn)
                   + so * __builtin_amdgcn_exp2f(mo - mn);
                mm = mn;
            }
            if (lrow == 0) {
                const int grow = row0 + 16 * h + 4 * lk + r;
                pm[grow * NSPLIT + q] = mm;
                ps[grow * NSPLIT + q] = ss;
            }
        }
}

// ---------------- kernel 2: per-row loss + atomic partial sum into out[0] ----------------
__global__ void jl_rowloss(const float* __restrict__ pm, const float* __restrict__ ps,
                           const float* __restrict__ pos, float* __restrict__ out) {
    __shared__ float red[256];
    const int t = threadIdx.x;
    const int row = blockIdx.x * 256 + t;
    float mb = NEG_BIG;
    #pragma unroll
    for (int qq = 0; qq < NSPLIT; ++qq) mb = fmaxf(mb, pm[row * NSPLIT + qq]);
    float st = 0.0f;
    #pragma unroll
    for (int qq = 0; qq < NSPLIT; ++qq)
        st += ps[row * NSPLIT + qq] * __builtin_amdgcn_exp2f(pm[row * NSPLIT + qq] - mb);
    red[t] = mb + __builtin_amdgcn_logf(st) - pos[row];
    __syncthreads();
    for (int off = 128; off > 0; off >>= 1) {
        if (t < off) red[t] += red[t + off];
        __syncthreads();
    }
    if (t == 0) atomicAdd(out, red[0] * (LN2 / (float)NROWS));
}

extern "C" void kernel_launch(void* const* d_in, const int* in_sizes, int n_in,
                              void* d_out, int out_size, void* d_ws, size_t ws_size,
                              hipStream_t stream) {
    const float* rep = (const float*)d_in[0];
    float* out = (float*)d_out;

    unsigned char* rbuf = (unsigned char*)d_ws;                  // 2 MB fp8
    float*  pm   = (float*)(rbuf + (size_t)NROWS * 512);
    float*  ps   = pm + NROWS * NSPLIT;
    float*  pos  = ps + NROWS * NSPLIT;

    hipMemsetAsync(out, 0, sizeof(float), stream);               // zero accumulator
    jl_cvt<<<(NROWS * 64) / 256, 256, 0, stream>>>(rep, rbuf);
    jl_main<<<32 * NSPLIT, 256, 0, stream>>>(rbuf, pm, ps, pos);
    jl_rowloss<<<NROWS / 256, 256, 0, stream>>>(pm, ps, pos, out);
}

// Round 18
// 35.211 us; speedup vs baseline: 1.3628x; 1.0579x over previous
//
#include <hip/hip_runtime.h>
#include <hip/hip_bf16.h>
#include <hip/hip_fp8.h>

// SimCLR NT-Xent loss v18 (final): R15 fp8 core byte-identical (best: 34.75us)
// + hardware-packed fp8 convert (v_cvt_pk_fp8_f32). Reduction = R15's
// rowloss(16 blocks) + final (no memset, no atomics).

#define NROWS 4096
#define DDIM  512
#define NSPLIT 24                // uneven splits: 16 x 5 tiles + 8 x 6 tiles (128 tiles)
#define BM 128                   // rows per block (4 waves x 32)
#define NEG_BIG (-3.0e38f)
#define SQRT_CSCALE 3.798282562f // sqrt(10*log2(e)); (sqrt(c)A)(sqrt(c)B) = c*sim
#define LN2 0.69314718055994530942f
#define THR 40.0f                // defer-max threshold (log2 units)

typedef float f32x4 __attribute__((ext_vector_type(4)));
typedef long  lx2   __attribute__((ext_vector_type(2)));

#define GLOAD_LDS16(g, l) __builtin_amdgcn_global_load_lds(                    \
    (const __attribute__((address_space(1))) void*)(g),                        \
    (__attribute__((address_space(3))) void*)(l), 16, 0, 0)

#define MFMA8(a, b, c) __builtin_amdgcn_mfma_f32_16x16x32_fp8_fp8((a), (b), (c), 0, 0, 0)

// ---------------- kernel 0: fp32 -> fp8 e4m3 (HW packed cvt), fragment-ordered ----------------
// out byte for (row, k): row*512 + lk*128 + kb*8 + e, where k = kb*32 + lk*8 + e.
// thread t (0..63 per row) handles k in [8t, 8t+8) = (kb = t>>2, lk = t&3).
__global__ void jl_cvt(const float* __restrict__ in, unsigned char* __restrict__ out) {
    const int i   = blockIdx.x * 256 + threadIdx.x;
    const int row = i >> 6;
    const int t   = i & 63;
    const float* src = in + (size_t)row * DDIM + t * 8;
    float4 x = *(const float4*)(src);
    float4 y = *(const float4*)(src + 4);
    int w0 = __builtin_amdgcn_cvt_pk_fp8_f32(x.x * SQRT_CSCALE, x.y * SQRT_CSCALE, 0, false);
    w0     = __builtin_amdgcn_cvt_pk_fp8_f32(x.z * SQRT_CSCALE, x.w * SQRT_CSCALE, w0, true);
    int w1 = __builtin_amdgcn_cvt_pk_fp8_f32(y.x * SQRT_CSCALE, y.y * SQRT_CSCALE, 0, false);
    w1     = __builtin_amdgcn_cvt_pk_fp8_f32(y.z * SQRT_CSCALE, y.w * SQRT_CSCALE, w1, true);
    uint2 pk = {(unsigned)w0, (unsigned)w1};
    *(uint2*)(out + (size_t)row * 512 + (t & 3) * 128 + (t >> 2) * 8) = pk;
}

// ---------------- kernel 1: fused fp8 GEMM + log2-sum-exp2 partials (R15 exact) ----------------
// grid = 32 rowblocks x 24 colsplits = 768 blocks (3/CU), 256 threads (4 waves).
// split q: tiles [tile0, tile0+NTq) of 32 cols x K512 each.
__global__ __launch_bounds__(256, 3) void jl_main(const unsigned char* __restrict__ rb,
                                                  float* __restrict__ pm,
                                                  float* __restrict__ ps,
                                                  float* __restrict__ pos) {
    // 2 buffers x 32 tile-cols x 512 B (fragment-ordered, XOR-swizzled 16B slots)
    __shared__ __align__(16) char smem[2][32][512];

    const int rbk   = blockIdx.x / NSPLIT;   // 0..31
    const int q     = blockIdx.x % NSPLIT;   // 0..23
    const int tile0 = (q < 16) ? 5 * q : 80 + 6 * (q - 16);
    const int NTq   = (q < 16) ? 5 : 6;

    const int wave = threadIdx.x >> 6;
    const int lane = threadIdx.x & 63;
    const int row0 = rbk * BM + wave * 32;   // wave's first row (32 rows)
    const int lrow = lane & 15;
    const int lk   = lane >> 4;
    const int swz  = (lrow & 7) << 4;        // read-side XOR (byte units)
    const char* rbb = (const char*)rb;       // fp8 row stride 512 B

    // A fragments: 32 longs = 64 VGPR. afA[kb] = A[row0+lrow][k=kb*32+lk*8+..]
    long afA[16], afB[16];
    {
        const char* ar = rbb + (size_t)(row0 + lrow) * 512 + lk * 128;
        #pragma unroll
        for (int j = 0; j < 8; ++j) {
            lx2 v = *(const lx2*)(ar + j * 16);
            lx2 w = *(const lx2*)(ar + 16 * 512 + j * 16);
            afA[2 * j] = v[0]; afA[2 * j + 1] = v[1];
            afB[2 * j] = w[0]; afB[2 * j + 1] = w[1];
        }
    }

    // staging: wave w stages tile-cols [8w, 8w+8) as 4 x 1KB gload_lds (2 cols each).
    // per-lane source: col c = base + (lane>>5), slot s = lane&31,
    // global byte = c*512 + (s*16 ^ ((c&7)<<4))  [inverse of the read swizzle]
#define STAGE(J)                                                               \
    do {                                                                       \
        _Pragma("unroll")                                                      \
        for (int i_ = 0; i_ < 4; ++i_) {                                       \
            const int lc_ = wave * 8 + 2 * i_;            /* local col pair */ \
            const int c_  = (tile0 + (J)) * 32 + lc_ + (lane >> 5);            \
            const char* g_ = rbb + (size_t)c_ * 512                            \
                             + (((lane & 31) * 16) ^ ((c_ & 7) << 4));         \
            GLOAD_LDS16(g_, &smem[(J) & 1][lc_][0]);                           \
        }                                                                      \
    } while (0)

    STAGE(0);

    float m[2][4], s[2][4];
    #pragma unroll
    for (int h = 0; h < 2; ++h)
        #pragma unroll
        for (int r = 0; r < 4; ++r) { m[h][r] = NEG_BIG; s[h][r] = 0.0f; }

    for (int jt = 0; jt < NTq; ++jt) {
        // race-free 2-phase: drain own stage loads, sync, then prefetch next
        asm volatile("s_waitcnt vmcnt(0)" ::: "memory");
        __builtin_amdgcn_s_barrier();
        __builtin_amdgcn_sched_barrier(0);
        if (jt + 1 < NTq) STAGE(jt + 1);

        const int cb = jt & 1;

        f32x4 a00 = {0.f,0.f,0.f,0.f}, a01 = {0.f,0.f,0.f,0.f};
        f32x4 a10 = {0.f,0.f,0.f,0.f}, a11 = {0.f,0.f,0.f,0.f};
        __builtin_amdgcn_s_setprio(1);
        #pragma unroll
        for (int j = 0; j < 8; ++j) {
            // b128 at fragment offset (lk*128 + j*16) ^ swz covers kb=2j, 2j+1
            lx2 b0 = *(const lx2*)(&smem[cb][lrow][0]      + ((lk * 128 + j * 16) ^ swz));
            lx2 b1 = *(const lx2*)(&smem[cb][16 + lrow][0] + ((lk * 128 + j * 16) ^ swz));
            a00 = MFMA8(afA[2 * j],     b0[0], a00);
            a10 = MFMA8(afB[2 * j],     b0[0], a10);
            a01 = MFMA8(afA[2 * j],     b1[0], a01);
            a11 = MFMA8(afB[2 * j],     b1[0], a11);
            a00 = MFMA8(afA[2 * j + 1], b0[1], a00);
            a10 = MFMA8(afB[2 * j + 1], b0[1], a10);
            a01 = MFMA8(afA[2 * j + 1], b1[1], a01);
            a11 = MFMA8(afB[2 * j + 1], b1[1], a11);
        }
        __builtin_amdgcn_s_setprio(0);

        // y[h][n]: row = row0 + h*16 + 4*lk + r,  col = ctile + n*16 + lrow
        f32x4 y[2][2] = {{a00, a01}, {a10, a11}};
        const int ctile = (tile0 + jt) * 32;   // wave-uniform absolute column

        // positive-pair tile (uniform, rare): partner of row i is i^2048
        if (ctile == (row0 ^ 2048)) {
            #pragma unroll
            for (int h = 0; h < 2; ++h)
                #pragma unroll
                for (int r = 0; r < 4; ++r)
                    if (lrow == 4 * lk + r)
                        pos[row0 + h * 16 + 4 * lk + r] = y[h][h][r];
        }

        if (ctile == row0) {
            // diagonal tile (1 per wave): mask col==row then full online update
            #pragma unroll
            for (int h = 0; h < 2; ++h)
                #pragma unroll
                for (int r = 0; r < 4; ++r) {
                    if (lrow == 4 * lk + r) y[h][h][r] = NEG_BIG;
                    float y0 = y[h][0][r], y1 = y[h][1][r];
                    float mn = fmaxf(m[h][r], fmaxf(y0, y1));
                    s[h][r] = s[h][r] * __builtin_amdgcn_exp2f(m[h][r] - mn)
                            + __builtin_amdgcn_exp2f(y0 - mn)
                            + __builtin_amdgcn_exp2f(y1 - mn);
                    m[h][r] = mn;
                }
        } else {
            float t[2][2][4];
            float dmax = NEG_BIG;
            #pragma unroll
            for (int h = 0; h < 2; ++h)
                #pragma unroll
                for (int n = 0; n < 2; ++n)
                    #pragma unroll
                    for (int r = 0; r < 4; ++r) {
                        t[h][n][r] = y[h][n][r] - m[h][r];
                        dmax = fmaxf(dmax, t[h][n][r]);
                    }
            if (__any(dmax > THR)) {
                #pragma unroll
                for (int h = 0; h < 2; ++h)
                    #pragma unroll
                    for (int r = 0; r < 4; ++r) {
                        float y0 = y[h][0][r], y1 = y[h][1][r];
                        float mn = fmaxf(m[h][r], fmaxf(y0, y1));
                        s[h][r] = s[h][r] * __builtin_amdgcn_exp2f(m[h][r] - mn)
                                + __builtin_amdgcn_exp2f(y0 - mn)
                                + __builtin_amdgcn_exp2f(y1 - mn);
                        m[h][r] = mn;
                    }
            } else {
                #pragma unroll
                for (int h = 0; h < 2; ++h)
                    #pragma unroll
                    for (int r = 0; r < 4; ++r)
                        s[h][r] += __builtin_amdgcn_exp2f(t[h][0][r])
                                 + __builtin_amdgcn_exp2f(t[h][1][r]);
            }
        }
    }
#undef STAGE

    // merge (m,s) across the 16 lanes of each row group, write partials
    #pragma unroll
    for (int h = 0; h < 2; ++h)
        #pragma unroll
        for (int r = 0; r < 4; ++r) {
            float mm = m[h][r], ss = s[h][r];
            #pragma unroll
            for (int off = 1; off < 16; off <<= 1) {
                float mo = __shfl_xor(mm, off, 64);
                float so = __shfl_xor(ss, off, 64);
                float mn = fmaxf(mm, mo);
                ss = ss * __builtin_amdgcn_exp2f(mm - mn)
                   + so * __builtin_amdgcn_exp2f(mo - mn);
                mm = mn;
            }
            if (lrow == 0) {
                const int grow = row0 + 16 * h + 4 * lk + r;
                pm[grow * NSPLIT + q] = mm;
                ps[grow * NSPLIT + q] = ss;
            }
        }
}

// ---------------- kernel 2a: per-row loss + per-block partial sum ----------------
__global__ void jl_rowloss(const float* __restrict__ pm, const float* __restrict__ ps,
                           const float* __restrict__ pos, float* __restrict__ part) {
    __shared__ float red[256];
    const int t = threadIdx.x;
    const int row = blockIdx.x * 256 + t;
    float mb = NEG_BIG;
    #pragma unroll
    for (int qq = 0; qq < NSPLIT; ++qq) mb = fmaxf(mb, pm[row * NSPLIT + qq]);
    float st = 0.0f;
    #pragma unroll
    for (int qq = 0; qq < NSPLIT; ++qq)
        st += ps[row * NSPLIT + qq] * __builtin_amdgcn_exp2f(pm[row * NSPLIT + qq] - mb);
    red[t] = mb + __builtin_amdgcn_logf(st) - pos[row];
    __syncthreads();
    for (int off = 128; off > 0; off >>= 1) {
        if (t < off) red[t] += red[t + off];
        __syncthreads();
    }
    if (t == 0) part[blockIdx.x] = red[0];
}

// ---------------- kernel 2b: final reduce ----------------
__global__ void jl_final(const float* __restrict__ part, float* __restrict__ out) {
    const int t = threadIdx.x;
    float v = (t < NROWS / 256) ? part[t] : 0.0f;
    #pragma unroll
    for (int off = 1; off < 16; off <<= 1) v += __shfl_xor(v, off, 64);
    if (t == 0) out[0] = v * (LN2 / (float)NROWS);
}

extern "C" void kernel_launch(void* const* d_in, const int* in_sizes, int n_in,
                              void* d_out, int out_size, void* d_ws, size_t ws_size,
                              hipStream_t stream) {
    const float* rep = (const float*)d_in[0];
    float* out = (float*)d_out;

    unsigned char* rbuf = (unsigned char*)d_ws;                  // 2 MB fp8
    float*  pm   = (float*)(rbuf + (size_t)NROWS * 512);
    float*  ps   = pm + NROWS * NSPLIT;
    float*  pos  = ps + NROWS * NSPLIT;
    float*  part = pos + NROWS;

    jl_cvt<<<(NROWS * 64) / 256, 256, 0, stream>>>(rep, rbuf);
    jl_main<<<32 * NSPLIT, 256, 0, stream>>>(rbuf, pm, ps, pos);
    jl_rowloss<<<NROWS / 256, 256, 0, stream>>>(pm, ps, pos, part);
    jl_final<<<1, 64, 0, stream>>>(part, out);
}